// Round 3
// baseline (291.699 us; speedup 1.0000x reference)
//
#include <hip/hip_runtime.h>

// GConv: out = spmm(A0, S) + spmm(A1, S) + bias,  S = x @ W
// N=100000, E=600000, F_IN=F_OUT=128.
// R8: top dispatch (pull 54us) < sum of unprofiled middle (~200us). Changes:
//   (1) gemm: B (=W^T bf16, 32KB) held in REGISTERS per wave (32x short8),
//       loaded once from L2-hot wt; A read direct-from-global in MFMA frag
//       pattern (16 rows x 128B coalesced segments). No LDS, no barriers,
//       no redundant 50MB Wt re-staging, no Bs bank conflicts.
//   (2) counting sort: order-free block bases via atomicAdd (1 kernel
//       replaces block_sum+scan_bsum+write_ptr); pull uses beg+count[wid].
//   (3) pos[] precomputed once coalesced; scatter filters on pos -> exact
//       XCD-ownership of rec regions (p = blockIdx&7) and ~40% less re-read
//       traffic vs row-filter scatter.
//   (4) pull gather loop unrolled 8-wide for MLP.

#define FDIM 128
#define EPB 2048   // edges examined per scatter block

typedef __attribute__((ext_vector_type(8))) short short8;
typedef __attribute__((ext_vector_type(4))) float floatx4;

__device__ __forceinline__ unsigned short f32_to_bf16(float f) {
    unsigned int u = __float_as_uint(f);
    unsigned int r = u + 0x7fffu + ((u >> 16) & 1u);   // RNE
    return (unsigned short)(r >> 16);
}

__device__ __forceinline__ float bf16_lo(unsigned int u) {
    return __uint_as_float((u & 0xffffu) << 16);
}
__device__ __forceinline__ float bf16_hi(unsigned int u) {
    return __uint_as_float(u & 0xffff0000u);
}

// ---------------- Wt[n][k] = bf16(W[k][n]) — 64KB, one-shot ----------------
__global__ __launch_bounds__(256) void wt_conv(const float* __restrict__ w,
                                               unsigned short* __restrict__ wt) {
    int idx = blockIdx.x * 256 + threadIdx.x;   // 0..16383
    int nn = idx >> 7, k = idx & 127;
    wt[idx] = f32_to_bf16(w[(size_t)k * FDIM + nn]);
}

// ---------------- GEMM: support(bf16) = x @ W, B-in-registers, no LDS ------
// One wave: 16 rows x 128 cols, K=128. b[nt][ks] = wt[nt*16+lr][ks*32+quad*8..+7]
__global__ __launch_bounds__(256) void gemm_reg(const float* __restrict__ x,
                                                const unsigned short* __restrict__ wt,
                                                unsigned short* __restrict__ support,
                                                int n) {
    const int tid = threadIdx.x;
    const int wv = tid >> 6, lane = tid & 63;
    const int quad = lane >> 4, lr = lane & 15;
    const int row0 = (blockIdx.x * 4 + wv) * 16;
    if (row0 >= n) return;

    // B fragments: 32 x 16B coalesced L2-hit loads (wave covers 16 rows x 64B)
    short8 b[8][4];
    #pragma unroll
    for (int nt = 0; nt < 8; ++nt)
        #pragma unroll
        for (int ks = 0; ks < 4; ++ks)
            b[nt][ks] = *(const short8*)(wt + (size_t)(nt * 16 + lr) * FDIM + ks * 32 + quad * 8);

    floatx4 acc[8];
    #pragma unroll
    for (int nt = 0; nt < 8; ++nt) acc[nt] = (floatx4)0.f;

    const int arow = row0 + lr;
    const bool rowok = arow < n;
    const float* xr = x + (size_t)arow * FDIM;

    // hoist all 8 A loads (16 rows x 128B contiguous segments per (ks,quad))
    float4 f[8];
    #pragma unroll
    for (int ks = 0; ks < 4; ++ks) {
        f[2 * ks]     = rowok ? *(const float4*)(xr + ks * 32 + quad * 8)     : make_float4(0.f,0.f,0.f,0.f);
        f[2 * ks + 1] = rowok ? *(const float4*)(xr + ks * 32 + quad * 8 + 4) : make_float4(0.f,0.f,0.f,0.f);
    }

    #pragma unroll
    for (int ks = 0; ks < 4; ++ks) {
        float4 lo = f[2 * ks], hi = f[2 * ks + 1];
        short8 a;
        a[0] = (short)f32_to_bf16(lo.x); a[1] = (short)f32_to_bf16(lo.y);
        a[2] = (short)f32_to_bf16(lo.z); a[3] = (short)f32_to_bf16(lo.w);
        a[4] = (short)f32_to_bf16(hi.x); a[5] = (short)f32_to_bf16(hi.y);
        a[6] = (short)f32_to_bf16(hi.z); a[7] = (short)f32_to_bf16(hi.w);
        #pragma unroll
        for (int nt = 0; nt < 8; ++nt)
            acc[nt] = __builtin_amdgcn_mfma_f32_16x16x32_bf16(a, b[nt][ks], acc[nt], 0, 0, 0);
    }

    #pragma unroll
    for (int i = 0; i < 4; ++i) {
        int row = row0 + quad * 4 + i;
        if (row < n) {
            #pragma unroll
            for (int nt = 0; nt < 8; ++nt)
                support[(size_t)row * FDIM + nt * 16 + lr] = f32_to_bf16(acc[nt][i]);
        }
    }
}

// ---------------- CSR build: hist(+rank) -> 1-kernel scan -> pos -> scatter
__global__ __launch_bounds__(256) void hist_rows(const int* __restrict__ rows0,
                                                 const int* __restrict__ rows1,
                                                 int* __restrict__ count,
                                                 int* __restrict__ rank, int E) {
    int gid = blockIdx.x * 256 + threadIdx.x;
    if (gid >= 2 * E) return;
    int r = (gid < E) ? rows0[gid] : rows1[gid - E];
    rank[gid] = atomicAdd(&count[r], 1);   // returned old value = rank in row
}

// block-wide inclusive scan of v over 256 threads (lds must hold 8 ints)
__device__ __forceinline__ int block_incl_scan(int v, int tid, int* lds) {
    int lane = tid & 63, wv = tid >> 6;
    #pragma unroll
    for (int d = 1; d < 64; d <<= 1) {
        int y = __shfl_up(v, d);
        if (lane >= d) v += y;
    }
    if (lane == 63) lds[wv] = v;
    __syncthreads();
    if (wv == 0 && lane < 4) {
        int s = lds[lane];
        #pragma unroll
        for (int d = 1; d < 4; d <<= 1) {
            int y = __shfl_up(s, d);
            if (lane >= d) s += y;
        }
        lds[4 + lane] = s;
    }
    __syncthreads();
    int add = (wv > 0) ? lds[4 + wv - 1] : 0;
    return v + add;
}

// counting sort needs disjoint correct ranges, not row-ordered ones:
// block base comes from an atomicAdd of the block total (order-free).
__global__ __launch_bounds__(256) void rowptr_scan(const int* __restrict__ count,
                                                   int* __restrict__ rowptr,
                                                   int* __restrict__ gcur, int n) {
    __shared__ int lds[8];
    __shared__ int base;
    int tid = threadIdx.x;
    int idx = blockIdx.x * 256 + tid;
    int v = (idx < n) ? count[idx] : 0;
    int inc = block_incl_scan(v, tid, lds);
    if (tid == 255) base = atomicAdd(gcur, inc);
    __syncthreads();
    if (idx < n) rowptr[idx] = base + inc - v;   // exclusive within block + base
}

__global__ __launch_bounds__(256) void compute_pos(const int* __restrict__ rows0,
                                                   const int* __restrict__ rows1,
                                                   const int* __restrict__ rank,
                                                   const int* __restrict__ rowptr,
                                                   int* __restrict__ pos, int E) {
    int gid = blockIdx.x * 256 + threadIdx.x;
    if (gid >= 2 * E) return;
    int r = (gid < E) ? rows0[gid] : rows1[gid - E];
    pos[gid] = rowptr[r] + rank[gid];
}

// block b: edge tile b>>3, rec-position partition p=b&7 (exact region
// [p*psize,(p+1)*psize) -> always written by XCD b%8=p -> L2-merged lines).
__global__ __launch_bounds__(256) void scatter_pos(
    const int* __restrict__ cols0, const float* __restrict__ vals0,
    const int* __restrict__ cols1, const float* __restrict__ vals1,
    const int* __restrict__ pos,
    int2* __restrict__ rec, int E, int psize) {
    const int p = blockIdx.x & 7;
    const int base = (blockIdx.x >> 3) * EPB;
    const int tid = threadIdx.x;
    #pragma unroll
    for (int it = 0; it < EPB / 256; ++it) {
        int gid = base + it * 256 + tid;
        if (gid < 2 * E) {
            int pv = pos[gid];
            if (pv / psize == p) {
                int c; float v;
                if (gid < E) { c = cols0[gid]; v = vals0[gid]; }
                else         { int e = gid - E; c = cols1[e]; v = vals1[e]; }
                rec[pv] = make_int2(c, __float_as_int(v));
            }
        }
    }
}

// ---------------- pull: wave per row; coalesced rec load + shfl broadcast --
__global__ __launch_bounds__(256) void pull_csr(const unsigned short* __restrict__ support,
                                                const int* __restrict__ rowptr,
                                                const int* __restrict__ count,
                                                const int2* __restrict__ rec,
                                                const float* __restrict__ bias,
                                                float* __restrict__ out, int n) {
    int wid = (blockIdx.x * 256 + threadIdx.x) >> 6;
    int lane = threadIdx.x & 63;
    if (wid >= n) return;
    int beg = rowptr[wid];
    int end = beg + count[wid];
    float ax = 0.f, ay = 0.f;
    const char* sp = (const char*)support;
    const unsigned loff = (unsigned)lane << 2;   // lane*4 bytes = 2 bf16 feats

    for (int base = beg; base < end; base += 64) {
        int m = end - base; if (m > 64) m = 64;
        long long pk = 0;
        if (lane < m) pk = *(const long long*)&rec[base + lane];  // 1 coalesced load
        int j = 0;
        for (; j + 8 <= m; j += 8) {
            long long p0 = __shfl(pk, j);
            long long p1 = __shfl(pk, j + 1);
            long long p2 = __shfl(pk, j + 2);
            long long p3 = __shfl(pk, j + 3);
            long long p4 = __shfl(pk, j + 4);
            long long p5 = __shfl(pk, j + 5);
            long long p6 = __shfl(pk, j + 6);
            long long p7 = __shfl(pk, j + 7);
            unsigned u0 = *(const unsigned*)(sp + (((unsigned)p0) << 8) + loff);
            unsigned u1 = *(const unsigned*)(sp + (((unsigned)p1) << 8) + loff);
            unsigned u2 = *(const unsigned*)(sp + (((unsigned)p2) << 8) + loff);
            unsigned u3 = *(const unsigned*)(sp + (((unsigned)p3) << 8) + loff);
            unsigned u4 = *(const unsigned*)(sp + (((unsigned)p4) << 8) + loff);
            unsigned u5 = *(const unsigned*)(sp + (((unsigned)p5) << 8) + loff);
            unsigned u6 = *(const unsigned*)(sp + (((unsigned)p6) << 8) + loff);
            unsigned u7 = *(const unsigned*)(sp + (((unsigned)p7) << 8) + loff);
            float v0 = __int_as_float((int)(p0 >> 32));
            float v1 = __int_as_float((int)(p1 >> 32));
            float v2 = __int_as_float((int)(p2 >> 32));
            float v3 = __int_as_float((int)(p3 >> 32));
            float v4 = __int_as_float((int)(p4 >> 32));
            float v5 = __int_as_float((int)(p5 >> 32));
            float v6 = __int_as_float((int)(p6 >> 32));
            float v7 = __int_as_float((int)(p7 >> 32));
            ax += v0 * bf16_lo(u0); ay += v0 * bf16_hi(u0);
            ax += v1 * bf16_lo(u1); ay += v1 * bf16_hi(u1);
            ax += v2 * bf16_lo(u2); ay += v2 * bf16_hi(u2);
            ax += v3 * bf16_lo(u3); ay += v3 * bf16_hi(u3);
            ax += v4 * bf16_lo(u4); ay += v4 * bf16_hi(u4);
            ax += v5 * bf16_lo(u5); ay += v5 * bf16_hi(u5);
            ax += v6 * bf16_lo(u6); ay += v6 * bf16_hi(u6);
            ax += v7 * bf16_lo(u7); ay += v7 * bf16_hi(u7);
        }
        for (; j + 4 <= m; j += 4) {
            long long p0 = __shfl(pk, j);
            long long p1 = __shfl(pk, j + 1);
            long long p2 = __shfl(pk, j + 2);
            long long p3 = __shfl(pk, j + 3);
            unsigned u0 = *(const unsigned*)(sp + (((unsigned)p0) << 8) + loff);
            unsigned u1 = *(const unsigned*)(sp + (((unsigned)p1) << 8) + loff);
            unsigned u2 = *(const unsigned*)(sp + (((unsigned)p2) << 8) + loff);
            unsigned u3 = *(const unsigned*)(sp + (((unsigned)p3) << 8) + loff);
            float v0 = __int_as_float((int)(p0 >> 32));
            float v1 = __int_as_float((int)(p1 >> 32));
            float v2 = __int_as_float((int)(p2 >> 32));
            float v3 = __int_as_float((int)(p3 >> 32));
            ax += v0 * bf16_lo(u0); ay += v0 * bf16_hi(u0);
            ax += v1 * bf16_lo(u1); ay += v1 * bf16_hi(u1);
            ax += v2 * bf16_lo(u2); ay += v2 * bf16_hi(u2);
            ax += v3 * bf16_lo(u3); ay += v3 * bf16_hi(u3);
        }
        for (; j < m; ++j) {
            long long p = __shfl(pk, j);
            unsigned u = *(const unsigned*)(sp + (((unsigned)p) << 8) + loff);
            float v = __int_as_float((int)(p >> 32));
            ax += v * bf16_lo(u); ay += v * bf16_hi(u);
        }
    }
    float2 b = *(const float2*)(bias + lane * 2);
    *(float2*)(out + (size_t)wid * FDIM + lane * 2) = make_float2(ax + b.x, ay + b.y);
}

// ---------------- fallback (ws too small): atomic scatter ------------------
__global__ __launch_bounds__(256) void init_bias(const float* __restrict__ bias,
                                                 float* __restrict__ out, int n) {
    int idx = blockIdx.x * 256 + threadIdx.x;
    int total = n * (FDIM / 4);
    if (idx < total) {
        int j = (idx & (FDIM / 4 - 1)) * 4;
        float4 b = *(const float4*)(bias + j);
        *(float4*)(out + (size_t)idx * 4) = b;
    }
}

__global__ __launch_bounds__(256) void scatter_bf16(
    const unsigned short* __restrict__ support,
    const int* __restrict__ rows0, const int* __restrict__ cols0, const float* __restrict__ vals0,
    const int* __restrict__ rows1, const int* __restrict__ cols1, const float* __restrict__ vals1,
    float* __restrict__ out, int E) {
    int gid = blockIdx.x * 256 + threadIdx.x;
    int lane = gid & 63;
    int eg = gid >> 6;
    if (eg >= 2 * E) return;
    int r, c; float v;
    if (eg < E) { r = rows0[eg]; c = cols0[eg]; v = vals0[eg]; }
    else        { int e = eg - E; r = rows1[e]; c = cols1[e]; v = vals1[e]; }
    unsigned int u = *(const unsigned int*)(support + (size_t)c * FDIM + lane * 2);
    float sx = bf16_lo(u);
    float sy = bf16_hi(u);
    float* op = out + (size_t)r * FDIM + lane * 2;
    atomicAdd(op,     sx * v);
    atomicAdd(op + 1, sy * v);
}

static inline size_t align256(size_t v) { return (v + 255) & ~(size_t)255; }

extern "C" void kernel_launch(void* const* d_in, const int* in_sizes, int n_in,
                              void* d_out, int out_size, void* d_ws, size_t ws_size,
                              hipStream_t stream) {
    const float* x     = (const float*)d_in[0];
    const float* w     = (const float*)d_in[1];
    const float* bias  = (const float*)d_in[2];
    const float* vals0 = (const float*)d_in[3];
    const float* vals1 = (const float*)d_in[4];
    const int*   rows0 = (const int*)d_in[5];
    const int*   cols0 = (const int*)d_in[6];
    const int*   rows1 = (const int*)d_in[7];
    const int*   cols1 = (const int*)d_in[8];
    const int n = in_sizes[0] / FDIM;
    const int E = in_sizes[3];
    float* out = (float*)d_out;

    const int NB = (n + 255) / 256;

    size_t off = 0;
    unsigned short* support = (unsigned short*)((char*)d_ws + off);
    off = align256(off + (size_t)n * FDIM * 2);
    unsigned short* wt = (unsigned short*)((char*)d_ws + off);
    off = align256(off + (size_t)FDIM * FDIM * 2);
    size_t count_off = off;
    int*  count  = (int*)((char*)d_ws + off);  off = align256(off + (size_t)n * 4);
    int*  gcur   = (int*)((char*)d_ws + off);  off = align256(off + 4);
    size_t zero_bytes = off - count_off;       // covers count + gcur
    int*  rowptr = (int*)((char*)d_ws + off);  off = align256(off + (size_t)n * 4);
    int*  rank   = (int*)((char*)d_ws + off);  off = align256(off + (size_t)2 * E * 4);
    int*  pos    = (int*)((char*)d_ws + off);  off = align256(off + (size_t)2 * E * 4);
    int2* rec    = (int2*)((char*)d_ws + off); off = align256(off + (size_t)2 * E * 8);

    wt_conv<<<(FDIM * FDIM) / 256, 256, 0, stream>>>(w, wt);
    gemm_reg<<<(n + 63) / 64, 256, 0, stream>>>(x, wt, support, n);

    if (off <= ws_size) {
        hipMemsetAsync((char*)d_ws + count_off, 0, zero_bytes, stream);
        int eb = (2 * E + 255) / 256;
        hist_rows<<<eb, 256, 0, stream>>>(rows0, rows1, count, rank, E);
        rowptr_scan<<<NB, 256, 0, stream>>>(count, rowptr, gcur, n);
        compute_pos<<<eb, 256, 0, stream>>>(rows0, rows1, rank, rowptr, pos, E);
        int psize = (2 * E + 7) / 8;
        int ntiles = (2 * E + EPB - 1) / EPB;
        scatter_pos<<<ntiles * 8, 256, 0, stream>>>(cols0, vals0, cols1, vals1,
                                                    pos, rec, E, psize);
        pull_csr<<<(n + 3) / 4, 256, 0, stream>>>(support, rowptr, count, rec, bias, out, n);
    } else {
        int total4 = n * (FDIM / 4);
        init_bias<<<(total4 + 255) / 256, 256, 0, stream>>>(bias, out, n);
        long long tthreads = 2LL * E * 64;
        int blocks = (int)((tthreads + 255) / 256);
        scatter_bf16<<<blocks, 256, 0, stream>>>(support, rows0, cols0, vals0,
                                                 rows1, cols1, vals1, out, E);
    }
}

// Round 4
// 264.430 us; speedup vs baseline: 1.1031x; 1.1031x over previous
//
#include <hip/hip_runtime.h>

// GConv: out = spmm(A0, S) + spmm(A1, S) + bias,  S = x @ W
// N=100000, E=600000, F_IN=F_OUT=128.
// R9: middle (everything but pull) = 237us vs ~60us traffic ideal. Changes:
//   (1) gemm: B-in-registers kept, but 64 rows/WAVE (4 row-tiles reuse the
//       32KB b[][] frags) -> wt L2 traffic 200MB->50MB (R8 regression fix).
//   (2) hist fused into the gemm dispatch (independent work): atomic-latency
//       hist blocks hide under compute-bound gemm blocks. -1 dispatch.
//   (3) compute_pos + pos[] removed: scatter filters on row-partition and
//       computes rowptr[r]+rank[gid] inline (rowptr gather is L2-hot).
//       Row partitions are compact rec regions (24KB chunks) -> XCD-owned
//       writes still merge in L2. -1 dispatch, -19MB traffic.
//   (4) count/gcur zeroing folded into prep (wt_conv) kernel. -1 dispatch.
//   Pipeline: prep -> gemm_hist -> rowptr_scan -> scatter_row -> pull.

#define FDIM 128
#define EPB 2048   // edges examined per scatter block

typedef __attribute__((ext_vector_type(8))) short short8;
typedef __attribute__((ext_vector_type(4))) float floatx4;

__device__ __forceinline__ unsigned short f32_to_bf16(float f) {
    unsigned int u = __float_as_uint(f);
    unsigned int r = u + 0x7fffu + ((u >> 16) & 1u);   // RNE
    return (unsigned short)(r >> 16);
}

__device__ __forceinline__ float bf16_lo(unsigned int u) {
    return __uint_as_float((u & 0xffffu) << 16);
}
__device__ __forceinline__ float bf16_hi(unsigned int u) {
    return __uint_as_float(u & 0xffff0000u);
}

// ---------------- prep: Wt[n][k] = bf16(W[k][n]) + zero count/gcur ---------
__global__ __launch_bounds__(256) void prep(const float* __restrict__ w,
                                            unsigned short* __restrict__ wt,
                                            int* __restrict__ zero_ptr, int zero_ints) {
    int bid = blockIdx.x;
    if (bid < 64) {
        int idx = bid * 256 + threadIdx.x;   // 0..16383
        int nn = idx >> 7, k = idx & 127;
        wt[idx] = f32_to_bf16(w[(size_t)k * FDIM + nn]);
    } else {
        int idx = (bid - 64) * 256 + threadIdx.x;
        if (idx < zero_ints) zero_ptr[idx] = 0;
    }
}

// ---------------- fused: GEMM (64 rows/wave, B-in-reg) + edge histogram ----
// blocks [0,GB): gemm; blocks [GB,GB+HB): hist (independent, overlapped).
__global__ __launch_bounds__(256) void gemm_hist(const float* __restrict__ x,
                                                 const unsigned short* __restrict__ wt,
                                                 unsigned short* __restrict__ support,
                                                 int n,
                                                 const int* __restrict__ rows0,
                                                 const int* __restrict__ rows1,
                                                 int* __restrict__ count,
                                                 int* __restrict__ rank,
                                                 int E, int GB) {
    if ((int)blockIdx.x >= GB) {
        // ---- histogram: rank[gid] = old count of row ----
        int gid = (blockIdx.x - GB) * 256 + threadIdx.x;
        if (gid < 2 * E) {
            int r = (gid < E) ? rows0[gid] : rows1[gid - E];
            rank[gid] = atomicAdd(&count[r], 1);
        }
        return;
    }
    // ---- gemm: block covers 256 rows; wave wv covers 64 rows (4 tiles) ----
    const int tid = threadIdx.x;
    const int wv = tid >> 6, lane = tid & 63;
    const int quad = lane >> 4, lr = lane & 15;
    const int rbase = blockIdx.x * 256 + wv * 64;
    if (rbase >= n) return;

    // B fragments: 32 x 16B coalesced L2-hit loads, reused by 4 row-tiles
    short8 b[8][4];
    #pragma unroll
    for (int nt = 0; nt < 8; ++nt)
        #pragma unroll
        for (int ks = 0; ks < 4; ++ks)
            b[nt][ks] = *(const short8*)(wt + (size_t)(nt * 16 + lr) * FDIM + ks * 32 + quad * 8);

    for (int t = 0; t < 4; ++t) {
        const int row0 = rbase + t * 16;
        if (row0 >= n) break;
        const int arow = row0 + lr;
        const bool rowok = arow < n;
        const float* xr = x + (size_t)arow * FDIM;

        floatx4 acc[8];
        #pragma unroll
        for (int nt = 0; nt < 8; ++nt) acc[nt] = (floatx4)0.f;

        #pragma unroll
        for (int ks = 0; ks < 4; ++ks) {
            float4 lo = rowok ? *(const float4*)(xr + ks * 32 + quad * 8)     : make_float4(0.f,0.f,0.f,0.f);
            float4 hi = rowok ? *(const float4*)(xr + ks * 32 + quad * 8 + 4) : make_float4(0.f,0.f,0.f,0.f);
            short8 a;
            a[0] = (short)f32_to_bf16(lo.x); a[1] = (short)f32_to_bf16(lo.y);
            a[2] = (short)f32_to_bf16(lo.z); a[3] = (short)f32_to_bf16(lo.w);
            a[4] = (short)f32_to_bf16(hi.x); a[5] = (short)f32_to_bf16(hi.y);
            a[6] = (short)f32_to_bf16(hi.z); a[7] = (short)f32_to_bf16(hi.w);
            #pragma unroll
            for (int nt = 0; nt < 8; ++nt)
                acc[nt] = __builtin_amdgcn_mfma_f32_16x16x32_bf16(a, b[nt][ks], acc[nt], 0, 0, 0);
        }

        #pragma unroll
        for (int i = 0; i < 4; ++i) {
            int row = row0 + quad * 4 + i;
            if (row < n) {
                #pragma unroll
                for (int nt = 0; nt < 8; ++nt)
                    support[(size_t)row * FDIM + nt * 16 + lr] = f32_to_bf16(acc[nt][i]);
            }
        }
    }
}

// block-wide inclusive scan of v over 256 threads (lds must hold 8 ints)
__device__ __forceinline__ int block_incl_scan(int v, int tid, int* lds) {
    int lane = tid & 63, wv = tid >> 6;
    #pragma unroll
    for (int d = 1; d < 64; d <<= 1) {
        int y = __shfl_up(v, d);
        if (lane >= d) v += y;
    }
    if (lane == 63) lds[wv] = v;
    __syncthreads();
    if (wv == 0 && lane < 4) {
        int s = lds[lane];
        #pragma unroll
        for (int d = 1; d < 4; d <<= 1) {
            int y = __shfl_up(s, d);
            if (lane >= d) s += y;
        }
        lds[4 + lane] = s;
    }
    __syncthreads();
    int add = (wv > 0) ? lds[4 + wv - 1] : 0;
    return v + add;
}

// counting sort needs disjoint correct ranges, not row-ordered ones:
// block base comes from an atomicAdd of the block total (order-free).
__global__ __launch_bounds__(256) void rowptr_scan(const int* __restrict__ count,
                                                   int* __restrict__ rowptr,
                                                   int* __restrict__ gcur, int n) {
    __shared__ int lds[8];
    __shared__ int base;
    int tid = threadIdx.x;
    int idx = blockIdx.x * 256 + tid;
    int v = (idx < n) ? count[idx] : 0;
    int inc = block_incl_scan(v, tid, lds);
    if (tid == 255) base = atomicAdd(gcur, inc);
    __syncthreads();
    if (idx < n) rowptr[idx] = base + inc - v;   // exclusive within block + base
}

// block b: edge tile b>>3, row-partition p=b&7. Row partitions map to
// compact rec chunks (256-row scan blocks are contiguous) -> each chunk
// written by one XCD (p == blockIdx%8) -> L2-merged writebacks.
__global__ __launch_bounds__(256) void scatter_row(
    const int* __restrict__ rows0, const int* __restrict__ cols0, const float* __restrict__ vals0,
    const int* __restrict__ rows1, const int* __restrict__ cols1, const float* __restrict__ vals1,
    const int* __restrict__ rank, const int* __restrict__ rowptr,
    int2* __restrict__ rec, int E, int nper) {
    const int p = blockIdx.x & 7;
    const int base = (blockIdx.x >> 3) * EPB;
    const int tid = threadIdx.x;
    #pragma unroll
    for (int it = 0; it < EPB / 256; ++it) {
        int gid = base + it * 256 + tid;
        if (gid < 2 * E) {
            int r = (gid < E) ? rows0[gid] : rows1[gid - E];
            if (r / nper == p) {
                int c; float v;
                if (gid < E) { c = cols0[gid]; v = vals0[gid]; }
                else         { int e = gid - E; c = cols1[e]; v = vals1[e]; }
                rec[rowptr[r] + rank[gid]] = make_int2(c, __float_as_int(v));
            }
        }
    }
}

// ---------------- pull: wave per row; coalesced rec load + shfl broadcast --
__global__ __launch_bounds__(256) void pull_csr(const unsigned short* __restrict__ support,
                                                const int* __restrict__ rowptr,
                                                const int* __restrict__ count,
                                                const int2* __restrict__ rec,
                                                const float* __restrict__ bias,
                                                float* __restrict__ out, int n) {
    int wid = (blockIdx.x * 256 + threadIdx.x) >> 6;
    int lane = threadIdx.x & 63;
    if (wid >= n) return;
    int beg = rowptr[wid];
    int end = beg + count[wid];
    float ax = 0.f, ay = 0.f;
    const char* sp = (const char*)support;
    const unsigned loff = (unsigned)lane << 2;   // lane*4 bytes = 2 bf16 feats

    for (int base = beg; base < end; base += 64) {
        int m = end - base; if (m > 64) m = 64;
        long long pk = 0;
        if (lane < m) pk = *(const long long*)&rec[base + lane];  // 1 coalesced load
        int j = 0;
        for (; j + 8 <= m; j += 8) {
            long long p0 = __shfl(pk, j);
            long long p1 = __shfl(pk, j + 1);
            long long p2 = __shfl(pk, j + 2);
            long long p3 = __shfl(pk, j + 3);
            long long p4 = __shfl(pk, j + 4);
            long long p5 = __shfl(pk, j + 5);
            long long p6 = __shfl(pk, j + 6);
            long long p7 = __shfl(pk, j + 7);
            unsigned u0 = *(const unsigned*)(sp + (((unsigned)p0) << 8) + loff);
            unsigned u1 = *(const unsigned*)(sp + (((unsigned)p1) << 8) + loff);
            unsigned u2 = *(const unsigned*)(sp + (((unsigned)p2) << 8) + loff);
            unsigned u3 = *(const unsigned*)(sp + (((unsigned)p3) << 8) + loff);
            unsigned u4 = *(const unsigned*)(sp + (((unsigned)p4) << 8) + loff);
            unsigned u5 = *(const unsigned*)(sp + (((unsigned)p5) << 8) + loff);
            unsigned u6 = *(const unsigned*)(sp + (((unsigned)p6) << 8) + loff);
            unsigned u7 = *(const unsigned*)(sp + (((unsigned)p7) << 8) + loff);
            float v0 = __int_as_float((int)(p0 >> 32));
            float v1 = __int_as_float((int)(p1 >> 32));
            float v2 = __int_as_float((int)(p2 >> 32));
            float v3 = __int_as_float((int)(p3 >> 32));
            float v4 = __int_as_float((int)(p4 >> 32));
            float v5 = __int_as_float((int)(p5 >> 32));
            float v6 = __int_as_float((int)(p6 >> 32));
            float v7 = __int_as_float((int)(p7 >> 32));
            ax += v0 * bf16_lo(u0); ay += v0 * bf16_hi(u0);
            ax += v1 * bf16_lo(u1); ay += v1 * bf16_hi(u1);
            ax += v2 * bf16_lo(u2); ay += v2 * bf16_hi(u2);
            ax += v3 * bf16_lo(u3); ay += v3 * bf16_hi(u3);
            ax += v4 * bf16_lo(u4); ay += v4 * bf16_hi(u4);
            ax += v5 * bf16_lo(u5); ay += v5 * bf16_hi(u5);
            ax += v6 * bf16_lo(u6); ay += v6 * bf16_hi(u6);
            ax += v7 * bf16_lo(u7); ay += v7 * bf16_hi(u7);
        }
        for (; j + 4 <= m; j += 4) {
            long long p0 = __shfl(pk, j);
            long long p1 = __shfl(pk, j + 1);
            long long p2 = __shfl(pk, j + 2);
            long long p3 = __shfl(pk, j + 3);
            unsigned u0 = *(const unsigned*)(sp + (((unsigned)p0) << 8) + loff);
            unsigned u1 = *(const unsigned*)(sp + (((unsigned)p1) << 8) + loff);
            unsigned u2 = *(const unsigned*)(sp + (((unsigned)p2) << 8) + loff);
            unsigned u3 = *(const unsigned*)(sp + (((unsigned)p3) << 8) + loff);
            float v0 = __int_as_float((int)(p0 >> 32));
            float v1 = __int_as_float((int)(p1 >> 32));
            float v2 = __int_as_float((int)(p2 >> 32));
            float v3 = __int_as_float((int)(p3 >> 32));
            ax += v0 * bf16_lo(u0); ay += v0 * bf16_hi(u0);
            ax += v1 * bf16_lo(u1); ay += v1 * bf16_hi(u1);
            ax += v2 * bf16_lo(u2); ay += v2 * bf16_hi(u2);
            ax += v3 * bf16_lo(u3); ay += v3 * bf16_hi(u3);
        }
        for (; j < m; ++j) {
            long long p = __shfl(pk, j);
            unsigned u = *(const unsigned*)(sp + (((unsigned)p) << 8) + loff);
            float v = __int_as_float((int)(p >> 32));
            ax += v * bf16_lo(u); ay += v * bf16_hi(u);
        }
    }
    float2 b = *(const float2*)(bias + lane * 2);
    *(float2*)(out + (size_t)wid * FDIM + lane * 2) = make_float2(ax + b.x, ay + b.y);
}

// ---------------- fallback (ws too small): atomic scatter ------------------
__global__ __launch_bounds__(256) void init_bias(const float* __restrict__ bias,
                                                 float* __restrict__ out, int n) {
    int idx = blockIdx.x * 256 + threadIdx.x;
    int total = n * (FDIM / 4);
    if (idx < total) {
        int j = (idx & (FDIM / 4 - 1)) * 4;
        float4 b = *(const float4*)(bias + j);
        *(float4*)(out + (size_t)idx * 4) = b;
    }
}

__global__ __launch_bounds__(256) void scatter_bf16(
    const unsigned short* __restrict__ support,
    const int* __restrict__ rows0, const int* __restrict__ cols0, const float* __restrict__ vals0,
    const int* __restrict__ rows1, const int* __restrict__ cols1, const float* __restrict__ vals1,
    float* __restrict__ out, int E) {
    int gid = blockIdx.x * 256 + threadIdx.x;
    int lane = gid & 63;
    int eg = gid >> 6;
    if (eg >= 2 * E) return;
    int r, c; float v;
    if (eg < E) { r = rows0[eg]; c = cols0[eg]; v = vals0[eg]; }
    else        { int e = eg - E; r = rows1[e]; c = cols1[e]; v = vals1[e]; }
    unsigned int u = *(const unsigned int*)(support + (size_t)c * FDIM + lane * 2);
    float sx = bf16_lo(u);
    float sy = bf16_hi(u);
    float* op = out + (size_t)r * FDIM + lane * 2;
    atomicAdd(op,     sx * v);
    atomicAdd(op + 1, sy * v);
}

static inline size_t align256(size_t v) { return (v + 255) & ~(size_t)255; }

extern "C" void kernel_launch(void* const* d_in, const int* in_sizes, int n_in,
                              void* d_out, int out_size, void* d_ws, size_t ws_size,
                              hipStream_t stream) {
    const float* x     = (const float*)d_in[0];
    const float* w     = (const float*)d_in[1];
    const float* bias  = (const float*)d_in[2];
    const float* vals0 = (const float*)d_in[3];
    const float* vals1 = (const float*)d_in[4];
    const int*   rows0 = (const int*)d_in[5];
    const int*   cols0 = (const int*)d_in[6];
    const int*   rows1 = (const int*)d_in[7];
    const int*   cols1 = (const int*)d_in[8];
    const int n = in_sizes[0] / FDIM;
    const int E = in_sizes[3];
    float* out = (float*)d_out;

    const int NB = (n + 255) / 256;

    size_t off = 0;
    unsigned short* support = (unsigned short*)((char*)d_ws + off);
    off = align256(off + (size_t)n * FDIM * 2);
    unsigned short* wt = (unsigned short*)((char*)d_ws + off);
    off = align256(off + (size_t)FDIM * FDIM * 2);
    size_t count_off = off;
    int*  count  = (int*)((char*)d_ws + off);  off = align256(off + (size_t)n * 4);
    int*  gcur   = (int*)((char*)d_ws + off);  off = align256(off + 4);
    size_t zero_bytes = off - count_off;       // covers count + gcur
    int*  rowptr = (int*)((char*)d_ws + off);  off = align256(off + (size_t)n * 4);
    int*  rank   = (int*)((char*)d_ws + off);  off = align256(off + (size_t)2 * E * 4);
    int2* rec    = (int2*)((char*)d_ws + off); off = align256(off + (size_t)2 * E * 8);

    const bool fits = off <= ws_size;
    const int GB = (n + 255) / 256;                  // gemm blocks (256 rows each)
    const int HB = fits ? (2 * E + 255) / 256 : 0;   // hist blocks

    // prep: wt conversion + zero(count,gcur) (zero only when build path used)
    int zero_ints = fits ? (int)(zero_bytes / 4) : 0;
    int zb = (zero_ints + 255) / 256;
    prep<<<64 + zb, 256, 0, stream>>>(w, wt, (int*)((char*)d_ws + count_off), zero_ints);

    gemm_hist<<<GB + HB, 256, 0, stream>>>(x, wt, support, n,
                                           rows0, rows1, count, rank, E, GB);

    if (fits) {
        rowptr_scan<<<NB, 256, 0, stream>>>(count, rowptr, gcur, n);
        int nper = (n + 7) / 8;
        int ntiles = (2 * E + EPB - 1) / EPB;
        scatter_row<<<ntiles * 8, 256, 0, stream>>>(rows0, cols0, vals0,
                                                    rows1, cols1, vals1,
                                                    rank, rowptr, rec, E, nper);
        pull_csr<<<(n + 3) / 4, 256, 0, stream>>>(support, rowptr, count, rec, bias, out, n);
    } else {
        int total4 = n * (FDIM / 4);
        init_bias<<<(total4 + 255) / 256, 256, 0, stream>>>(bias, out, n);
        long long tthreads = 2LL * E * 64;
        int blocks = (int)((tthreads + 255) / 256);
        scatter_bf16<<<blocks, 256, 0, stream>>>(support, rows0, cols0, vals0,
                                                 rows1, cols1, vals1, out, E);
    }
}